// Round 4
// baseline (115.731 us; speedup 1.0000x reference)
//
#include <hip/hip_runtime.h>
#include <math.h>

#define MPTS 8192
#define DIMS 32
#define QB   64      // queries per block
#define NW   16      // waves per block (1024 threads)
#define HALF 4096    // candidate-split: each block scans half the candidate rows

typedef __bf16 bf16x8 __attribute__((ext_vector_type(8)));
typedef float  f32x4  __attribute__((ext_vector_type(4)));

// Insert v into sorted-DESCENDING top-4 (t0>=t1>=t2>=t3): 1 max + 3 med3.
__device__ __forceinline__ void top4L_insert(float v, float& t0, float& t1, float& t2, float& t3) {
    float n0 = fmaxf(t0, v);
    float n1 = __builtin_amdgcn_fmed3f(v, t0, t1);
    float n2 = __builtin_amdgcn_fmed3f(v, t1, t2);
    float n3 = __builtin_amdgcn_fmed3f(v, t2, t3);
    t0 = n0; t1 = n1; t2 = n2; t3 = n3;
}

// Merge two sorted-desc 4-lists -> sorted-desc top-4 (bitonic half-cleaner + merge, 12 ops).
__device__ __forceinline__ void top4_merge(float u0, float u1, float u2, float u3,
                                           float& t0, float& t1, float& t2, float& t3) {
    float m0 = fmaxf(t0, u3), m1 = fmaxf(t1, u2), m2 = fmaxf(t2, u1), m3 = fmaxf(t3, u0);
    float a = fmaxf(m0, m2), c = fminf(m0, m2);
    float b = fmaxf(m1, m3), d = fminf(m1, m3);
    t0 = fmaxf(a, b); t1 = fminf(a, b); t2 = fmaxf(c, d); t3 = fminf(c, d);
}

__device__ __forceinline__ unsigned short f32_to_bf16_rne(float x) {
    unsigned u = __float_as_uint(x);
    unsigned r = u + 0x7FFFu + ((u >> 16) & 1u);
    return (unsigned short)(r >> 16);
}

// K1: bf16 conversion of P,Q + norms pre-scaled by -0.5 ( -|x|^2/2 ). Also zeroes totals.
__global__ void prep_kernel(const float* __restrict__ P, const float* __restrict__ Q,
                            unsigned short* __restrict__ Phi, unsigned short* __restrict__ Qhi,
                            float* __restrict__ normP, float* __restrict__ normQ,
                            int* __restrict__ tots) {
    if (blockIdx.x == 0 && threadIdx.x < 2) tots[threadIdx.x] = 0;
    int t = blockIdx.x * 256 + threadIdx.x;          // 0 .. 65535
    int mat = t >> 15;                               // 0 = P, 1 = Q
    int idx = t & 32767;
    int r = idx >> 2, seg = idx & 3;                 // 8 elements per thread
    const float* X = mat ? Q : P;
    unsigned short* Xhi = mat ? Qhi : Phi;
    float* nX = mat ? normQ : normP;

    const float* src = X + (size_t)r * DIMS + seg * 8;
    float4 v0 = *(const float4*)(src);
    float4 v1 = *(const float4*)(src + 4);
    float f[8] = {v0.x, v0.y, v0.z, v0.w, v1.x, v1.y, v1.z, v1.w};

    float p = 0.f;
#pragma unroll
    for (int k = 0; k < 8; ++k) p = fmaf(f[k], f[k], p);
    p += __shfl_xor(p, 1);
    p += __shfl_xor(p, 2);      // seg groups of 4 are lane-aligned
    if (seg == 0) nX[r] = -0.5f * p;

    unsigned short h[8];
#pragma unroll
    for (int k = 0; k < 8; ++k) h[k] = f32_to_bf16_rne(f[k]);
    uint4 ph;
    ph.x = (unsigned)h[0] | ((unsigned)h[1] << 16);
    ph.y = (unsigned)h[2] | ((unsigned)h[3] << 16);
    ph.z = (unsigned)h[4] | ((unsigned)h[5] << 16);
    ph.w = (unsigned)h[6] | ((unsigned)h[7] << 16);
    *(uint4*)(Xhi + (size_t)r * DIMS + seg * 8) = ph;
}

// K2a: knn partials over candidate half h. grid (128, 2 dirs, 2 halves) = 512 blocks,
// 16 waves -> 2 blocks/CU = 8 waves/SIMD (per-CU VMEM conserved vs the fused version:
// each block scans HALF the rows). Block owns 64 queries; lane holds 4 B-frags
// (queries q+16b) -> 4 top-4 chains; wave w scans rows [h*4096+w*256, +256) = 8 iters.
// s-domain: s = dot - na/2 (larger == closer). Quad merge in-register (shfl_xor 16/32),
// block merge 16 wave-lists -> exact per-half top-4 written to partials.
__global__ __launch_bounds__(1024, 8)
void knn_kernel(const unsigned short* __restrict__ Phi, const unsigned short* __restrict__ Qhi,
                const float* __restrict__ normP, const float* __restrict__ normQ,
                float4* __restrict__ partials) {
    __shared__ float4 ldsM[NW * QB];     // 16 KB: [wave][query] top-4
    const int dir = blockIdx.y, h = blockIdx.z;
    const unsigned short* Yhi = dir ? Phi : Qhi;
    const float* nY = dir ? normP : normQ;
    const int tid = threadIdx.x;
    const int w = tid >> 6, l = tid & 63, q = l & 15, quad = l >> 4;
    const int q0 = blockIdx.x * QB;

    bf16x8 bh[4];
#pragma unroll
    for (int b = 0; b < 4; ++b)
        bh[b] = *(const bf16x8*)(Yhi + (size_t)(q0 + b * 16 + q) * DIMS + quad * 8);

    float t0[4], t1[4], t2[4], t3[4];
#pragma unroll
    for (int b = 0; b < 4; ++b) t0[b] = t1[b] = t2[b] = t3[b] = -3.4e38f;
    {
        const int base = h * HALF + w * 256;
        const unsigned short* pH = Yhi + ((size_t)base + q) * DIMS + quad * 8;
        const float* pN = nY + base + quad * 4;
        for (int i = 0; i < 8; ++i) {
            bf16x8 ah0 = *(const bf16x8*)(pH);
            bf16x8 ah1 = *(const bf16x8*)(pH + 16 * DIMS);
            float4 nA0 = *(const float4*)(pN);
            float4 nA1 = *(const float4*)(pN + 16);
            pH += 32 * DIMS; pN += 32;
            f32x4 c0v = {nA0.x, nA0.y, nA0.z, nA0.w};
            f32x4 c1v = {nA1.x, nA1.y, nA1.z, nA1.w};
#pragma unroll
            for (int b = 0; b < 4; ++b) {
                f32x4 a0 = __builtin_amdgcn_mfma_f32_16x16x32_bf16(ah0, bh[b], c0v, 0, 0, 0);
                f32x4 a1 = __builtin_amdgcn_mfma_f32_16x16x32_bf16(ah1, bh[b], c1v, 0, 0, 0);
#pragma unroll
                for (int r = 0; r < 4; ++r) top4L_insert(a0[r], t0[b], t1[b], t2[b], t3[b]);
#pragma unroll
                for (int r = 0; r < 4; ++r) top4L_insert(a1[r], t0[b], t1[b], t2[b], t3[b]);
            }
        }
    }
    // in-register quad merge (lanes q, q+16, q+32, q+48 hold disjoint candidate rows)
#pragma unroll
    for (int b = 0; b < 4; ++b) {
        float u0 = __shfl_xor(t0[b], 16), u1 = __shfl_xor(t1[b], 16);
        float u2 = __shfl_xor(t2[b], 16), u3 = __shfl_xor(t3[b], 16);
        top4_merge(u0, u1, u2, u3, t0[b], t1[b], t2[b], t3[b]);
        u0 = __shfl_xor(t0[b], 32); u1 = __shfl_xor(t1[b], 32);
        u2 = __shfl_xor(t2[b], 32); u3 = __shfl_xor(t3[b], 32);
        top4_merge(u0, u1, u2, u3, t0[b], t1[b], t2[b], t3[b]);
        if (quad == 0)
            ldsM[w * QB + q + b * 16] = make_float4(t0[b], t1[b], t2[b], t3[b]);
    }
    __syncthreads();
    if (tid < QB) {
        float a0 = -3.4e38f, a1 = a0, a2 = a0, a3 = a0;
#pragma unroll
        for (int u = 0; u < NW; ++u) {
            float4 v = ldsM[u * QB + tid];
            top4L_insert(v.x, a0, a1, a2, a3);
            top4L_insert(v.y, a0, a1, a2, a3);
            top4L_insert(v.z, a0, a1, a2, a3);
            top4L_insert(v.w, a0, a1, a2, a3);
        }
        partials[(dir * 2 + h) * MPTS + q0 + tid] = make_float4(a0, a1, a2, a3);
    }
}

// K2b: tau + count over candidate half h. Same 512-block grid. Each block merges the
// two per-half top-4s for its 64 queries (cheap, redundant across halves), derives
// tau/nusq, then counts s >= tau over its half of X. Per-half counts written without
// atomics; exact block totals atomicAdd'd into tots.
__global__ __launch_bounds__(1024, 8)
void count_kernel(const unsigned short* __restrict__ Phi, const unsigned short* __restrict__ Qhi,
                  const float* __restrict__ normP, const float* __restrict__ normQ,
                  const float4* __restrict__ partials,
                  float* __restrict__ nusqP, float* __restrict__ nusqQ,
                  int* __restrict__ countP2, int* __restrict__ countQ2,
                  int* __restrict__ tots) {
    __shared__ float ldsTau[QB];
    __shared__ int   ldsC[NW * QB];      // 4 KB
    const int dir = blockIdx.y, h = blockIdx.z;
    const unsigned short *Yhi, *Xhi; const float *nY, *nX; float* nusqOut;
    int* cntOut; int* totOut;
    if (dir == 0) { Yhi = Qhi; nY = normQ; Xhi = Phi; nX = normP;
                    nusqOut = nusqQ; cntOut = countQ2; totOut = &tots[1]; }
    else          { Yhi = Phi; nY = normP; Xhi = Qhi; nX = normQ;
                    nusqOut = nusqP; cntOut = countP2; totOut = &tots[0]; }
    const int tid = threadIdx.x;
    const int w = tid >> 6, l = tid & 63, q = l & 15, quad = l >> 4;
    const int q0 = blockIdx.x * QB;

    bf16x8 bh[4];
#pragma unroll
    for (int b = 0; b < 4; ++b)
        bh[b] = *(const bf16x8*)(Yhi + (size_t)(q0 + b * 16 + q) * DIMS + quad * 8);

    if (tid < QB) {
        float4 pa = partials[(dir * 2 + 0) * MPTS + q0 + tid];
        float4 pb = partials[(dir * 2 + 1) * MPTS + q0 + tid];
        float a0 = pa.x, a1 = pa.y, a2 = pa.z, a3 = pa.w;
        top4_merge(pb.x, pb.y, pb.z, pb.w, a0, a1, a2, a3);
        float nb = -2.0f * nY[q0 + tid];               // |y|^2
        float nu2 = fmaxf(nb - 2.0f * a3, 1e-12f);     // sq-domain nu^2, clamped
        nusqOut[q0 + tid] = nu2;                       // both halves write identical value
        ldsTau[tid] = 0.5f * (nb - nu2);               // s-domain threshold
    }
    __syncthreads();
    float tau[4];
#pragma unroll
    for (int b = 0; b < 4; ++b) tau[b] = ldsTau[q + b * 16];

    int cnt[4] = {0, 0, 0, 0};
    {
        const int base = h * HALF + w * 256;
        const unsigned short* pH = Xhi + ((size_t)base + q) * DIMS + quad * 8;
        const float* pN = nX + base + quad * 4;
        for (int i = 0; i < 8; ++i) {
            bf16x8 ah0 = *(const bf16x8*)(pH);
            bf16x8 ah1 = *(const bf16x8*)(pH + 16 * DIMS);
            float4 nA0 = *(const float4*)(pN);
            float4 nA1 = *(const float4*)(pN + 16);
            pH += 32 * DIMS; pN += 32;
            f32x4 c0v = {nA0.x, nA0.y, nA0.z, nA0.w};
            f32x4 c1v = {nA1.x, nA1.y, nA1.z, nA1.w};
#pragma unroll
            for (int b = 0; b < 4; ++b) {
                f32x4 a0 = __builtin_amdgcn_mfma_f32_16x16x32_bf16(ah0, bh[b], c0v, 0, 0, 0);
                f32x4 a1 = __builtin_amdgcn_mfma_f32_16x16x32_bf16(ah1, bh[b], c1v, 0, 0, 0);
#pragma unroll
                for (int r = 0; r < 4; ++r) {
                    cnt[b] += (a0[r] >= tau[b]) ? 1 : 0;
                    cnt[b] += (a1[r] >= tau[b]) ? 1 : 0;
                }
            }
        }
    }
#pragma unroll
    for (int b = 0; b < 4; ++b) {
        int c = cnt[b] + __shfl_xor(cnt[b], 16);
        c += __shfl_xor(c, 32);
        if (quad == 0) ldsC[w * QB + q + b * 16] = c;
    }
    __syncthreads();
    if (tid < QB) {
        int s = 0;
#pragma unroll
        for (int u = 0; u < NW; ++u) s += ldsC[u * QB + tid];
        cntOut[h * MPTS + q0 + tid] = s;
        int rsum = s;                                   // block total (wave 0)
        rsum += __shfl_xor(rsum, 1);
        rsum += __shfl_xor(rsum, 2);
        rsum += __shfl_xor(rsum, 4);
        rsum += __shfl_xor(rsum, 8);
        rsum += __shfl_xor(rsum, 16);
        rsum += __shfl_xor(rsum, 32);
        if (tid == 0) atomicAdd(totOut, rsum);          // exact integer sum
    }
}

// K3: epilogue, single pass (totals precomputed). Counts = sum of the two halves
// (exact integer); same 512 threads / same per-term op order -> identical r accumulation.
__global__ __launch_bounds__(512)
void final_kernel(const int* __restrict__ countP2, const int* __restrict__ countQ2,
                  const float* __restrict__ nusqP, const float* __restrict__ nusqQ,
                  const int* __restrict__ tots, float* __restrict__ out) {
    __shared__ double rdQ[8], rdP[8];
    const int tid = threadIdx.x;
    const int w = tid >> 6, l = tid & 63;

    const float kq_term = 3.0f / 24576.0f;
    float kpQ = (float)tots[1] + 1e-20f;
    float kpP = (float)tots[0] + 1e-20f;
    double rQ = 0.0, rP = 0.0;
    for (int j = tid; j < MPTS; j += 512) {
        {
            int cq = countQ2[j] + countQ2[MPTS + j];
            float nu = sqrtf(nusqQ[j]);
            float x = nu * nu; x *= x; x *= x; x *= x; x *= x;   // nu^32
            float inv = 1.0f / (x + 1e-20f);
            float p_den = ((float)cq / kpQ) * inv;
            p_den = fminf(fmaxf(p_den, 1e-20f), 1e10f);
            float q_den = kq_term * inv;
            q_den = fminf(fmaxf(q_den, 1e-20f), 1e10f);
            rQ += (double)((p_den / q_den) * kq_term);
        }
        {
            int cp = countP2[j] + countP2[MPTS + j];
            float nu = sqrtf(nusqP[j]);
            float x = nu * nu; x *= x; x *= x; x *= x; x *= x;
            float inv = 1.0f / (x + 1e-20f);
            float p_den = ((float)cp / kpP) * inv;
            p_den = fminf(fmaxf(p_den, 1e-20f), 1e10f);
            float q_den = kq_term * inv;
            q_den = fminf(fmaxf(q_den, 1e-20f), 1e10f);
            rP += (double)((p_den / q_den) * kq_term);
        }
    }
#pragma unroll
    for (int o = 32; o > 0; o >>= 1) { rQ += __shfl_down(rQ, o); rP += __shfl_down(rP, o); }
    if (l == 0) { rdQ[w] = rQ; rdP[w] = rP; }
    __syncthreads();
    if (tid == 0) {
        double RQ = 0.0, RP = 0.0;
#pragma unroll
        for (int u = 0; u < 8; ++u) { RQ += rdQ[u]; RP += rdP[u]; }
        float divP = fmaxf(0.0f, logf((float)RQ));    // alpha=2 -> 1/(alpha-1)=1
        float divQ = fmaxf(0.0f, logf((float)RP));
        out[0] = fmaxf(divP, divQ);
    }
}

extern "C" void kernel_launch(void* const* d_in, const int* in_sizes, int n_in,
                              void* d_out, int out_size, void* d_ws, size_t ws_size,
                              hipStream_t stream) {
    const float* P = (const float*)d_in[0];
    const float* Q = (const float*)d_in[1];
    float* out = (float*)d_out;

    unsigned short* Phi = (unsigned short*)d_ws;                 // 512 KB
    unsigned short* Qhi = Phi + MPTS * DIMS;                     // 512 KB
    float4* partials = (float4*)(Qhi + MPTS * DIMS);             // 512 KB (16B aligned)
    float* normP = (float*)(partials + 4 * MPTS);
    float* normQ = normP + MPTS;
    float* nusqP = normQ + MPTS;
    float* nusqQ = nusqP + MPTS;
    int* countP2 = (int*)(nusqQ + MPTS);                         // 2 halves x MPTS
    int* countQ2 = countP2 + 2 * MPTS;
    int* tots    = countQ2 + 2 * MPTS;                           // [0]=sum cP, [1]=sum cQ

    prep_kernel<<<256, 256, 0, stream>>>(P, Q, Phi, Qhi, normP, normQ, tots);
    knn_kernel<<<dim3(MPTS / QB, 2, 2), 1024, 0, stream>>>(Phi, Qhi, normP, normQ, partials);
    count_kernel<<<dim3(MPTS / QB, 2, 2), 1024, 0, stream>>>(Phi, Qhi, normP, normQ, partials,
                                                             nusqP, nusqQ, countP2, countQ2, tots);
    final_kernel<<<1, 512, 0, stream>>>(countP2, countQ2, nusqP, nusqQ, tots, out);
}

// Round 5
// 102.298 us; speedup vs baseline: 1.1313x; 1.1313x over previous
//
#include <hip/hip_runtime.h>
#include <math.h>

#define MPTS 8192
#define DIMS 32
#define QB   64      // queries per block
#define NW   16      // waves per block (1024 threads)

typedef __bf16 bf16x8 __attribute__((ext_vector_type(8)));
typedef float  f32x4  __attribute__((ext_vector_type(4)));

// Insert v into sorted-DESCENDING top-4 (t0>=t1>=t2>=t3): 1 max + 3 med3.
__device__ __forceinline__ void top4L_insert(float v, float& t0, float& t1, float& t2, float& t3) {
    float n0 = fmaxf(t0, v);
    float n1 = __builtin_amdgcn_fmed3f(v, t0, t1);
    float n2 = __builtin_amdgcn_fmed3f(v, t1, t2);
    float n3 = __builtin_amdgcn_fmed3f(v, t2, t3);
    t0 = n0; t1 = n1; t2 = n2; t3 = n3;
}

// Merge two sorted-desc 4-lists -> sorted-desc top-4 (bitonic half-cleaner + merge, 12 ops).
__device__ __forceinline__ void top4_merge(float u0, float u1, float u2, float u3,
                                           float& t0, float& t1, float& t2, float& t3) {
    float m0 = fmaxf(t0, u3), m1 = fmaxf(t1, u2), m2 = fmaxf(t2, u1), m3 = fmaxf(t3, u0);
    float a = fmaxf(m0, m2), c = fminf(m0, m2);
    float b = fmaxf(m1, m3), d = fminf(m1, m3);
    t0 = fmaxf(a, b); t1 = fminf(a, b); t2 = fmaxf(c, d); t3 = fminf(c, d);
}

__device__ __forceinline__ unsigned short f32_to_bf16_rne(float x) {
    unsigned u = __float_as_uint(x);
    unsigned r = u + 0x7FFFu + ((u >> 16) & 1u);
    return (unsigned short)(r >> 16);
}

// K1: bf16 conversion of P,Q + norms pre-scaled by -0.5 ( -|x|^2/2 ). Also zeroes totals.
__global__ void prep_kernel(const float* __restrict__ P, const float* __restrict__ Q,
                            unsigned short* __restrict__ Phi, unsigned short* __restrict__ Qhi,
                            float* __restrict__ normP, float* __restrict__ normQ,
                            int* __restrict__ tots) {
    if (blockIdx.x == 0 && threadIdx.x < 2) tots[threadIdx.x] = 0;
    int t = blockIdx.x * 256 + threadIdx.x;          // 0 .. 65535
    int mat = t >> 15;                               // 0 = P, 1 = Q
    int idx = t & 32767;
    int r = idx >> 2, seg = idx & 3;                 // 8 elements per thread
    const float* X = mat ? Q : P;
    unsigned short* Xhi = mat ? Qhi : Phi;
    float* nX = mat ? normQ : normP;

    const float* src = X + (size_t)r * DIMS + seg * 8;
    float4 v0 = *(const float4*)(src);
    float4 v1 = *(const float4*)(src + 4);
    float f[8] = {v0.x, v0.y, v0.z, v0.w, v1.x, v1.y, v1.z, v1.w};

    float p = 0.f;
#pragma unroll
    for (int k = 0; k < 8; ++k) p = fmaf(f[k], f[k], p);
    p += __shfl_xor(p, 1);
    p += __shfl_xor(p, 2);      // seg groups of 4 are lane-aligned
    if (seg == 0) nX[r] = -0.5f * p;

    unsigned short h[8];
#pragma unroll
    for (int k = 0; k < 8; ++k) h[k] = f32_to_bf16_rne(f[k]);
    uint4 ph;
    ph.x = (unsigned)h[0] | ((unsigned)h[1] << 16);
    ph.y = (unsigned)h[2] | ((unsigned)h[3] << 16);
    ph.z = (unsigned)h[4] | ((unsigned)h[5] << 16);
    ph.w = (unsigned)h[6] | ((unsigned)h[7] << 16);
    *(uint4*)(Xhi + (size_t)r * DIMS + seg * 8) = ph;
}

// K2: fused knn+count. grid (MPTS/QB=128, 2 dirs), block 1024 thr = 16 waves, 1 block/CU.
// Block owns 64 queries; lane holds 4 B-frags (queries q+16b) -> 4 top-4 chains.
// Wave w scans rows [w*512,(w+1)*512): per iter 2 row loads feed 8 MFMAs -> 32 inserts.
// BOTH feeds of the dependency chain (A-rows AND accumulator-init norms) rotate one
// iteration ahead in registers; #pragma unroll 2 caps code size (I-cache). Norms read
// from global (round-0-best; LDS staging measured neutral-negative).
// s-domain: s = dot - na/2 (larger == closer). Quad-lists merged in-register via
// shfl_xor(16/32) + bitonic merge; phase 2 counts s >= tau; block totals atomicAdd'd.
__global__ __launch_bounds__(1024, 4)
void fused_kernel(const unsigned short* __restrict__ Phi, const unsigned short* __restrict__ Qhi,
                  const float* __restrict__ normP, const float* __restrict__ normQ,
                  float* __restrict__ nusqP, float* __restrict__ nusqQ,
                  int* __restrict__ countP, int* __restrict__ countQ,
                  int* __restrict__ tots) {
    __shared__ float4 ldsM[NW * QB];     // 16 KB: [wave][query] top-4
    __shared__ int    ldsC[NW * QB];     //  4 KB: [wave][query] counts
    __shared__ float  ldsTau[QB];
    const unsigned short *Yhi, *Xhi; const float *nY, *nX; float* nusqOut;
    int* cntOut; int* totOut;
    if (blockIdx.y == 0) { Yhi = Qhi; nY = normQ; Xhi = Phi; nX = normP;
                           nusqOut = nusqQ; cntOut = countQ; totOut = &tots[1]; } // k_p for div_p
    else                 { Yhi = Phi; nY = normP; Xhi = Qhi; nX = normQ;
                           nusqOut = nusqP; cntOut = countP; totOut = &tots[0]; }
    const int tid = threadIdx.x;
    const int w = tid >> 6, l = tid & 63, q = l & 15, quad = l >> 4;
    const int q0 = blockIdx.x * QB;

    // 4 B-frags: query rows q0 + 16*b + q; k-octet = quad
    bf16x8 bh[4];
#pragma unroll
    for (int b = 0; b < 4; ++b)
        bh[b] = *(const bf16x8*)(Yhi + (size_t)(q0 + b * 16 + q) * DIMS + quad * 8);

    // ---------- phase 1: knn over Y ----------
    float t0[4], t1[4], t2[4], t3[4];
#pragma unroll
    for (int b = 0; b < 4; ++b) t0[b] = t1[b] = t2[b] = t3[b] = -3.4e38f;
    {
        const unsigned short* pH = Yhi + ((size_t)(w * 512) + q) * DIMS + quad * 8;
        const float* pN = nY + w * 512 + quad * 4;
        bf16x8 ah0 = *(const bf16x8*)(pH);
        bf16x8 ah1 = *(const bf16x8*)(pH + 16 * DIMS);
        float4 nA0 = *(const float4*)(pN);
        float4 nA1 = *(const float4*)(pN + 16);
#pragma unroll 2
        for (int i = 0; i < 16; ++i) {
            bf16x8 ch0 = ah0, ch1 = ah1;
            float4 cn0 = nA0, cn1 = nA1;
            if (i < 15) {                              // rotate next iter's feeds
                ah0 = *(const bf16x8*)(pH + 32 * DIMS);
                ah1 = *(const bf16x8*)(pH + 48 * DIMS);
                nA0 = *(const float4*)(pN + 32);
                nA1 = *(const float4*)(pN + 48);
            }
            pH += 32 * DIMS; pN += 32;
            f32x4 c0v = {cn0.x, cn0.y, cn0.z, cn0.w};
            f32x4 c1v = {cn1.x, cn1.y, cn1.z, cn1.w};
#pragma unroll
            for (int b = 0; b < 4; ++b) {
                f32x4 a0 = __builtin_amdgcn_mfma_f32_16x16x32_bf16(ch0, bh[b], c0v, 0, 0, 0);
                f32x4 a1 = __builtin_amdgcn_mfma_f32_16x16x32_bf16(ch1, bh[b], c1v, 0, 0, 0);
#pragma unroll
                for (int r = 0; r < 4; ++r) top4L_insert(a0[r], t0[b], t1[b], t2[b], t3[b]);
#pragma unroll
                for (int r = 0; r < 4; ++r) top4L_insert(a1[r], t0[b], t1[b], t2[b], t3[b]);
            }
        }
    }
    // in-register quad merge (lanes q, q+16, q+32, q+48 hold disjoint candidate rows)
#pragma unroll
    for (int b = 0; b < 4; ++b) {
        float u0 = __shfl_xor(t0[b], 16), u1 = __shfl_xor(t1[b], 16);
        float u2 = __shfl_xor(t2[b], 16), u3 = __shfl_xor(t3[b], 16);
        top4_merge(u0, u1, u2, u3, t0[b], t1[b], t2[b], t3[b]);
        u0 = __shfl_xor(t0[b], 32); u1 = __shfl_xor(t1[b], 32);
        u2 = __shfl_xor(t2[b], 32); u3 = __shfl_xor(t3[b], 32);
        top4_merge(u0, u1, u2, u3, t0[b], t1[b], t2[b], t3[b]);
        if (quad == 0)
            ldsM[w * QB + q + b * 16] = make_float4(t0[b], t1[b], t2[b], t3[b]);
    }
    __syncthreads();
    // block merge: 16 wave-lists per query -> tau
    if (tid < QB) {
        float a0 = -3.4e38f, a1 = a0, a2 = a0, a3 = a0;
#pragma unroll
        for (int u = 0; u < NW; ++u) {
            float4 v = ldsM[u * QB + tid];
            top4L_insert(v.x, a0, a1, a2, a3);
            top4L_insert(v.y, a0, a1, a2, a3);
            top4L_insert(v.z, a0, a1, a2, a3);
            top4L_insert(v.w, a0, a1, a2, a3);
        }
        float nb = -2.0f * nY[q0 + tid];               // |y|^2
        float nu2 = fmaxf(nb - 2.0f * a3, 1e-12f);     // sq-domain nu^2, clamped
        nusqOut[q0 + tid] = nu2;
        ldsTau[tid] = 0.5f * (nb - nu2);               // s-domain threshold
    }
    __syncthreads();
    float tau[4];
#pragma unroll
    for (int b = 0; b < 4; ++b) tau[b] = ldsTau[q + b * 16];

    // ---------- phase 2: count over X ----------
    int cnt[4] = {0, 0, 0, 0};
    {
        const unsigned short* pH = Xhi + ((size_t)(w * 512) + q) * DIMS + quad * 8;
        const float* pN = nX + w * 512 + quad * 4;
        bf16x8 ah0 = *(const bf16x8*)(pH);
        bf16x8 ah1 = *(const bf16x8*)(pH + 16 * DIMS);
        float4 nA0 = *(const float4*)(pN);
        float4 nA1 = *(const float4*)(pN + 16);
#pragma unroll 2
        for (int i = 0; i < 16; ++i) {
            bf16x8 ch0 = ah0, ch1 = ah1;
            float4 cn0 = nA0, cn1 = nA1;
            if (i < 15) {                              // rotate next iter's feeds
                ah0 = *(const bf16x8*)(pH + 32 * DIMS);
                ah1 = *(const bf16x8*)(pH + 48 * DIMS);
                nA0 = *(const float4*)(pN + 32);
                nA1 = *(const float4*)(pN + 48);
            }
            pH += 32 * DIMS; pN += 32;
            f32x4 c0v = {cn0.x, cn0.y, cn0.z, cn0.w};
            f32x4 c1v = {cn1.x, cn1.y, cn1.z, cn1.w};
#pragma unroll
            for (int b = 0; b < 4; ++b) {
                f32x4 a0 = __builtin_amdgcn_mfma_f32_16x16x32_bf16(ch0, bh[b], c0v, 0, 0, 0);
                f32x4 a1 = __builtin_amdgcn_mfma_f32_16x16x32_bf16(ch1, bh[b], c1v, 0, 0, 0);
#pragma unroll
                for (int r = 0; r < 4; ++r) {
                    cnt[b] += (a0[r] >= tau[b]) ? 1 : 0;
                    cnt[b] += (a1[r] >= tau[b]) ? 1 : 0;
                }
            }
        }
    }
    // quad reduce in-register, then [wave][query] LDS
#pragma unroll
    for (int b = 0; b < 4; ++b) {
        int c = cnt[b] + __shfl_xor(cnt[b], 16);
        c += __shfl_xor(c, 32);
        if (quad == 0) ldsC[w * QB + q + b * 16] = c;
    }
    __syncthreads();
    if (tid < QB) {
        int s = 0;
#pragma unroll
        for (int u = 0; u < NW; ++u) s += ldsC[u * QB + tid];
        cntOut[q0 + tid] = s;
        int rsum = s;                                   // block total (wave 0)
        rsum += __shfl_xor(rsum, 1);
        rsum += __shfl_xor(rsum, 2);
        rsum += __shfl_xor(rsum, 4);
        rsum += __shfl_xor(rsum, 8);
        rsum += __shfl_xor(rsum, 16);
        rsum += __shfl_xor(rsum, 32);
        if (tid == 0) atomicAdd(totOut, rsum);          // exact integer sum
    }
}

// K3a: epilogue partials, 16 blocks x 512 thr (one j per thread). Per-block double
// partial sums are deterministic (fixed shuffle-tree order); written to dparts.
__global__ __launch_bounds__(512)
void final_partial(const int* __restrict__ countP, const int* __restrict__ countQ,
                   const float* __restrict__ nusqP, const float* __restrict__ nusqQ,
                   const int* __restrict__ tots, double* __restrict__ dparts) {
    __shared__ double rdQ[8], rdP[8];
    const int tid = threadIdx.x, b = blockIdx.x;
    const int w = tid >> 6, l = tid & 63;
    const int j = b * 512 + tid;

    const float kq_term = 3.0f / 24576.0f;
    float kpQ = (float)tots[1] + 1e-20f;
    float kpP = (float)tots[0] + 1e-20f;
    double rQ, rP;
    {
        float nu = sqrtf(nusqQ[j]);
        float x = nu * nu; x *= x; x *= x; x *= x; x *= x;   // nu^32
        float inv = 1.0f / (x + 1e-20f);
        float p_den = ((float)countQ[j] / kpQ) * inv;
        p_den = fminf(fmaxf(p_den, 1e-20f), 1e10f);
        float q_den = kq_term * inv;
        q_den = fminf(fmaxf(q_den, 1e-20f), 1e10f);
        rQ = (double)((p_den / q_den) * kq_term);
    }
    {
        float nu = sqrtf(nusqP[j]);
        float x = nu * nu; x *= x; x *= x; x *= x; x *= x;
        float inv = 1.0f / (x + 1e-20f);
        float p_den = ((float)countP[j] / kpP) * inv;
        p_den = fminf(fmaxf(p_den, 1e-20f), 1e10f);
        float q_den = kq_term * inv;
        q_den = fminf(fmaxf(q_den, 1e-20f), 1e10f);
        rP = (double)((p_den / q_den) * kq_term);
    }
#pragma unroll
    for (int o = 32; o > 0; o >>= 1) { rQ += __shfl_down(rQ, o); rP += __shfl_down(rP, o); }
    if (l == 0) { rdQ[w] = rQ; rdP[w] = rP; }
    __syncthreads();
    if (tid == 0) {
        double RQ = 0.0, RP = 0.0;
#pragma unroll
        for (int u = 0; u < 8; ++u) { RQ += rdQ[u]; RP += rdP[u]; }
        dparts[b] = RQ; dparts[16 + b] = RP;
    }
}

// K3b: tiny reduce, fixed summation order.
__global__ void final_reduce(const double* __restrict__ dparts, float* __restrict__ out) {
    if (threadIdx.x == 0) {
        double RQ = 0.0, RP = 0.0;
#pragma unroll
        for (int u = 0; u < 16; ++u) RQ += dparts[u];
#pragma unroll
        for (int u = 0; u < 16; ++u) RP += dparts[16 + u];
        float divP = fmaxf(0.0f, logf((float)RQ));    // alpha=2 -> 1/(alpha-1)=1
        float divQ = fmaxf(0.0f, logf((float)RP));
        out[0] = fmaxf(divP, divQ);
    }
}

extern "C" void kernel_launch(void* const* d_in, const int* in_sizes, int n_in,
                              void* d_out, int out_size, void* d_ws, size_t ws_size,
                              hipStream_t stream) {
    const float* P = (const float*)d_in[0];
    const float* Q = (const float*)d_in[1];
    float* out = (float*)d_out;

    unsigned short* Phi = (unsigned short*)d_ws;
    unsigned short* Qhi = Phi + MPTS * DIMS;
    float* normP = (float*)(Qhi + MPTS * DIMS);
    float* normQ = normP + MPTS;
    float* nusqP = normQ + MPTS;
    float* nusqQ = nusqP + MPTS;
    int* countP  = (int*)(nusqQ + MPTS);
    int* countQ  = countP + MPTS;
    int* tots    = countQ + MPTS;                     // [0]=sum countP, [1]=sum countQ
    double* dparts = (double*)(tots + 2);             // 32 doubles (8B aligned)

    prep_kernel<<<256, 256, 0, stream>>>(P, Q, Phi, Qhi, normP, normQ, tots);
    fused_kernel<<<dim3(MPTS / QB, 2), 1024, 0, stream>>>(Phi, Qhi, normP, normQ,
                                                          nusqP, nusqQ, countP, countQ, tots);
    final_partial<<<16, 512, 0, stream>>>(countP, countQ, nusqP, nusqQ, tots, dparts);
    final_reduce<<<1, 64, 0, stream>>>(dparts, out);
}